// Round 4
// baseline (199.027 us; speedup 1.0000x reference)
//
#include <hip/hip_runtime.h>
#include <hip/hip_bf16.h>

#define N_TAGS 128
#define T_LEN  256
#define BSZ    256
#define ROOT_T 126
#define END_T  127

typedef float f32x2 __attribute__((ext_vector_type(2)));
typedef float f32x4 __attribute__((ext_vector_type(4)));
typedef int   i32x4 __attribute__((ext_vector_type(4)));

#define FMA2(a, b, c) __builtin_elementwise_fma((a), (b), (c))

static __device__ __forceinline__ float rfl(float x) {
  return __int_as_float(__builtin_amdgcn_readfirstlane(__float_as_int(x)));
}

// Dot of LDS vector ps[0..127] (wave-uniform broadcast f32x4 reads) against two
// register-resident 128-vectors (E2[0..63] -> s0, E2[64..127] -> s1).
static __device__ __forceinline__ void dot2cols(const float* __restrict__ ps,
                                                const f32x2 (&E2)[128],
                                                float& s0, float& s1) {
  const f32x4* pv = (const f32x4*)ps;
  f32x2 a0 = {0.f,0.f}, a1 = {0.f,0.f}, a2 = {0.f,0.f}, a3 = {0.f,0.f};
  f32x2 b0 = {0.f,0.f}, b1 = {0.f,0.f}, b2 = {0.f,0.f}, b3 = {0.f,0.f};
  #pragma unroll
  for (int q = 0; q < 16; ++q) {
    const f32x4 p = pv[2*q];
    const f32x4 r = pv[2*q+1];
    f32x2 plo; plo.x = p.x; plo.y = p.y;
    f32x2 phi; phi.x = p.z; phi.y = p.w;
    f32x2 rlo; rlo.x = r.x; rlo.y = r.y;
    f32x2 rhi; rhi.x = r.z; rhi.y = r.w;
    a0 = FMA2(plo, E2[4*q+0], a0);      a1 = FMA2(phi, E2[4*q+1], a1);
    a2 = FMA2(rlo, E2[4*q+2], a2);      a3 = FMA2(rhi, E2[4*q+3], a3);
    b0 = FMA2(plo, E2[64+4*q+0], b0);   b1 = FMA2(phi, E2[64+4*q+1], b1);
    b2 = FMA2(rlo, E2[64+4*q+2], b2);   b3 = FMA2(rhi, E2[64+4*q+3], b3);
  }
  const f32x2 sa = (a0 + a1) + (a2 + a3);
  const f32x2 sb = (b0 + b1) + (b2 + b3);
  s0 = sa.x + sa.y;
  s1 = sb.x + sb.y;
}

// One block per batch, 128 threads = 2 waves.
// Wave 0: forward recurrence.  Lane l owns columns l and l+64 of E=exp(lt).
// Wave 1: backward recurrence. Lane l owns rows    l and l+64 of E.
// NO barrier inside the 128-step loops: each direction is one wave; LDS
// write->read visibility within a wave needs only lgkmcnt (in-order DS).
// Normalizer = lane0's state via v_readfirstlane (exact, no LDS round-trip).
__global__ __launch_bounds__(128, 1) void crf_fwd_kernel(
    const float* __restrict__ feats,   // [BSZ][T_LEN][N_TAGS]
    const int*   __restrict__ tags,    // [BSZ][T_LEN]
    const int*   __restrict__ mask,    // [BSZ][T_LEN]
    const float* __restrict__ lt,      // [N_TAGS][N_TAGS]
    float*       __restrict__ per_batch)
{
  const int b    = blockIdx.x;
  const int tid  = threadIdx.x;
  const int lane = tid & 63;
  const int wave = tid >> 6;

  __shared__ __align__(16) float psF[2][N_TAGS];
  __shared__ __align__(16) float psB[2][N_TAGS];
  __shared__ float stage[32 * 129];
  __shared__ float bb[N_TAGS];
  __shared__ float sred[2];

  const float* fb = feats + (size_t)b * T_LEN * N_TAGS;
  const int*   tb = tags  + b * T_LEN;

  // ---- sequence length: per-wave independent (prefix mask) ----
  int len;
  {
    const i32x4 mv = ((const i32x4*)(mask + b * T_LEN))[lane];
    int v = mv.x + mv.y + mv.z + mv.w;
    #pragma unroll
    for (int d = 1; d < 64; d <<= 1) v += __shfl_xor(v, d);
    len = __builtin_amdgcn_readfirstlane(v);
  }

  // ---- build register-resident E = exp(lt): exp computed cooperatively once ----
  f32x2 E2[128];
  #pragma unroll
  for (int c = 0; c < 4; ++c) {
    __syncthreads();
    #pragma unroll
    for (int rr = 0; rr < 32; ++rr)
      stage[rr * 129 + tid] = __expf(lt[(c * 32 + rr) * N_TAGS + tid]);
    __syncthreads();
    if (wave == 0) {                       // columns lane, lane+64
      #pragma unroll
      for (int k = 0; k < 16; ++k) {
        f32x2 e0, e1;
        e0.x = stage[(2*k)   * 129 + lane];      e0.y = stage[(2*k+1) * 129 + lane];
        e1.x = stage[(2*k)   * 129 + lane + 64]; e1.y = stage[(2*k+1) * 129 + lane + 64];
        E2[c*16 + k]      = e0;
        E2[64 + c*16 + k] = e1;
      }
    } else {                               // rows lane, lane+64
      if ((lane >> 5) == c) {
        const int rr = lane & 31;
        #pragma unroll
        for (int q = 0; q < 64; ++q) {
          f32x2 e; e.x = stage[rr*129 + 2*q]; e.y = stage[rr*129 + 2*q + 1];
          E2[q] = e;
        }
      }
      if (((lane + 64) >> 5) == c) {
        const int rr = lane & 31;
        #pragma unroll
        for (int q = 0; q < 64; ++q) {
          f32x2 e; e.x = stage[rr*129 + 2*q]; e.y = stage[rr*129 + 2*q + 1];
          E2[64 + q] = e;
        }
      }
    }
  }

  float st0, st1;

  if (wave == 0) {
    // ================= FORWARD: alpha, steps t = 1..128 =================
    st0 = lt[ROOT_T * N_TAGS + lane]      + fb[lane];
    st1 = lt[ROOT_T * N_TAGS + lane + 64] + fb[lane + 64];
    float fa0 = fb[1 * N_TAGS + lane], fa1 = fb[1 * N_TAGS + lane + 64];
    float fc0 = fb[2 * N_TAGS + lane], fc1 = fb[2 * N_TAGS + lane + 64];
    float m_cur = rfl(st0);
    psF[1][lane]      = __expf(st0 - m_cur);
    psF[1][lane + 64] = __expf(st1 - m_cur);

    #pragma unroll 1
    for (int k2 = 0; k2 < 64; ++k2) {
      {                                   // t = 2*k2+1 : read psF[1] -> write psF[0]
        const int t = 2 * k2 + 1;
        float s0, s1; dot2cols(psF[1], E2, s0, s1);
        const float nf0 = m_cur + __logf(s0) + fa0;
        const float nf1 = m_cur + __logf(s1) + fa1;
        if (t < len) { st0 = nf0; st1 = nf1; }
        fa0 = fc0; fa1 = fc1;
        fc0 = fb[(t + 2) * N_TAGS + lane]; fc1 = fb[(t + 2) * N_TAGS + lane + 64];
        const float m = rfl(st0);
        psF[0][lane]      = __expf(st0 - m);
        psF[0][lane + 64] = __expf(st1 - m);
        m_cur = m;
      }
      {                                   // t = 2*k2+2 : read psF[0] -> write psF[1]
        const int t = 2 * k2 + 2;
        float s0, s1; dot2cols(psF[0], E2, s0, s1);
        const float nf0 = m_cur + __logf(s0) + fa0;
        const float nf1 = m_cur + __logf(s1) + fa1;
        if (t < len) { st0 = nf0; st1 = nf1; }
        fa0 = fc0; fa1 = fc1;
        fc0 = fb[(t + 2) * N_TAGS + lane]; fc1 = fb[(t + 2) * N_TAGS + lane + 64];
        const float m = rfl(st0);
        psF[1][lane]      = __expf(st0 - m);
        psF[1][lane + 64] = __expf(st1 - m);
        m_cur = m;
      }
    }
    // st = alpha_128
  } else {
    // ================= BACKWARD: beta, steps t1 = 256..129 =================
    st0 = lt[lane * N_TAGS + END_T];            // beta_{len-1}[i] = lt[i][END]
    st1 = lt[(lane + 64) * N_TAGS + END_T];
    float fw0 = fb[255 * N_TAGS + lane], fw1 = fb[255 * N_TAGS + lane + 64];
    float fa0 = fb[254 * N_TAGS + lane], fa1 = fb[254 * N_TAGS + lane + 64];
    float fc0 = fb[253 * N_TAGS + lane], fc1 = fb[253 * N_TAGS + lane + 64];
    float m_cur = rfl(st0);
    psB[1][lane]      = __expf(st0 + fw0 - m_cur);   // consumed by always-inactive k=0
    psB[1][lane + 64] = __expf(st1 + fw1 - m_cur);

    #pragma unroll 1
    for (int k2 = 0; k2 < 64; ++k2) {
      {                                   // k = 2*k2 : read psB[1] -> write psB[0]
        const int k = 2 * k2;
        float s0, s1; dot2cols(psB[1], E2, s0, s1);
        const float nb0 = m_cur + __logf(s0);
        const float nb1 = m_cur + __logf(s1);
        if (256 - k < len) { st0 = nb0; st1 = nb1; }
        const float w0 = fa0, w1 = fa1;   // feat row 254-k
        fa0 = fc0; fa1 = fc1;
        fc0 = fb[(252 - k) * N_TAGS + lane]; fc1 = fb[(252 - k) * N_TAGS + lane + 64];
        const float m = rfl(st0);
        psB[0][lane]      = __expf(st0 + w0 - m);
        psB[0][lane + 64] = __expf(st1 + w1 - m);
        m_cur = m;
      }
      {                                   // k = 2*k2+1 : read psB[0] -> write psB[1]
        const int k = 2 * k2 + 1;
        float s0, s1; dot2cols(psB[0], E2, s0, s1);
        const float nb0 = m_cur + __logf(s0);
        const float nb1 = m_cur + __logf(s1);
        if (256 - k < len) { st0 = nb0; st1 = nb1; }
        const float w0 = fa0, w1 = fa1;
        fa0 = fc0; fa1 = fc1;
        fc0 = fb[(252 - k) * N_TAGS + lane]; fc1 = fb[(252 - k) * N_TAGS + lane + 64];
        const float m = rfl(st0);
        psB[1][lane]      = __expf(st0 + w0 - m);
        psB[1][lane + 64] = __expf(st1 + w1 - m);
        m_cur = m;
      }
    }
    // st = beta_128
    bb[lane]      = st0;
    bb[lane + 64] = st1;
  }
  __syncthreads();

  // ---- gold-path score: 2 timesteps per thread ----
  float c = 0.f;
  #pragma unroll
  for (int q = 0; q < 2; ++q) {
    const int t  = tid + q * N_TAGS;
    const int tg = tb[t];
    if (t == 0)                           c += lt[ROOT_T * N_TAGS + tg];
    if (t >= 1 && t < len)                c += lt[tb[t - 1] * N_TAGS + tg];
    if (t < len && t <= T_LEN - 2)        c += fb[t * N_TAGS + tg];
    if (t == len - 1)                     c += lt[tg * N_TAGS + END_T];
    if (t == T_LEN - 1 && len == T_LEN)   c += fb[t * N_TAGS + tg];
  }
  #pragma unroll
  for (int d = 1; d < 64; d <<= 1) c += __shfl_xor(c, d);
  if (lane == 0) sred[wave] = c;

  // ---- partition: logsumexp(alpha_128 + beta_128) on wave 0 ----
  float part = 0.f;
  if (wave == 0) {
    const float x0 = st0 + bb[lane];
    const float x1 = st1 + bb[lane + 64];
    float mw = fmaxf(x0, x1);
    #pragma unroll
    for (int d = 1; d < 64; d <<= 1) mw = fmaxf(mw, __shfl_xor(mw, d));
    float e = __expf(x0 - mw) + __expf(x1 - mw);
    #pragma unroll
    for (int d = 1; d < 64; d <<= 1) e += __shfl_xor(e, d);
    part = mw + __logf(e);
  }
  __syncthreads();

  if (tid == 0) per_batch[b] = part - (sred[0] + sred[1]);
}

// Deterministic final reduction: mean over 256 per-batch values.
__global__ __launch_bounds__(256) void crf_reduce_kernel(
    const float* __restrict__ per_batch, float* __restrict__ out)
{
  const int tid = threadIdx.x;
  float v = per_batch[tid] * (1.0f / BSZ);
  #pragma unroll
  for (int d = 1; d < 64; d <<= 1) v += __shfl_xor(v, d);
  __shared__ float r[4];
  if ((tid & 63) == 0) r[tid >> 6] = v;
  __syncthreads();
  if (tid == 0) out[0] = r[0] + r[1] + r[2] + r[3];
}

extern "C" void kernel_launch(void* const* d_in, const int* in_sizes, int n_in,
                              void* d_out, int out_size, void* d_ws, size_t ws_size,
                              hipStream_t stream) {
  (void)in_sizes; (void)n_in; (void)out_size; (void)ws_size;
  const float* feats = (const float*)d_in[0];
  const int*   tags  = (const int*)d_in[1];
  const int*   mask  = (const int*)d_in[2];
  const float* lt    = (const float*)d_in[3];
  float* per_batch = (float*)d_ws;   // 256 floats of scratch

  crf_fwd_kernel<<<BSZ, 128, 0, stream>>>(feats, tags, mask, lt, per_batch);
  crf_reduce_kernel<<<1, 256, 0, stream>>>(per_batch, (float*)d_out);
}

// Round 6
// 105.014 us; speedup vs baseline: 1.8952x; 1.8952x over previous
//
#include <hip/hip_runtime.h>
#include <hip/hip_bf16.h>

#define N_TAGS 128
#define T_LEN  256
#define BSZ    256
#define ROOT_T 126
#define END_T  127

typedef _Float16 h2 __attribute__((ext_vector_type(2)));
typedef _Float16 h8 __attribute__((ext_vector_type(8)));
typedef int   i32x4 __attribute__((ext_vector_type(4)));

static __device__ __forceinline__ h2 pkrtz(float a, float b) {
  return __builtin_bit_cast(h2, __builtin_amdgcn_cvt_pkrtz(a, b));
}

static __device__ __forceinline__ float fdot2(h2 a, h2 b, float c) {
#if __has_builtin(__builtin_amdgcn_fdot2)
  return __builtin_amdgcn_fdot2(a, b, c, false);
#else
  float d;
  asm("v_dot2_f32_f16 %0, %1, %2, %3" : "=v"(d) : "v"(a), "v"(b), "v"(c));
  return d;
#endif
}

static __device__ __forceinline__ float wave_max(float x) {
  #pragma unroll
  for (int d = 1; d < 64; d <<= 1) x = fmaxf(x, __shfl_xor(x, d));
  return x;
}

// 128-length dual dot: s0 = sum_k p[k]*EA[k], s1 = sum_k p[k]*EB[k].
// p read from LDS as 16 wave-uniform b128 broadcasts (64 h2), f32 accumulate.
static __device__ __forceinline__ void dot128(const h2* __restrict__ psv,
                                              const h2 (&EA)[64], const h2 (&EB)[64],
                                              float& s0, float& s1) {
  const h8* pv = (const h8*)psv;
  float a0=0.f,a1=0.f,a2=0.f,a3=0.f, b0=0.f,b1=0.f,b2=0.f,b3=0.f;
  #pragma unroll
  for (int r = 0; r < 16; ++r) {
    const h8 v = pv[r];
    const h2 p0 = __builtin_shufflevector(v, v, 0, 1);
    const h2 p1 = __builtin_shufflevector(v, v, 2, 3);
    const h2 p2 = __builtin_shufflevector(v, v, 4, 5);
    const h2 p3 = __builtin_shufflevector(v, v, 6, 7);
    a0 = fdot2(p0, EA[4*r+0], a0);  a1 = fdot2(p1, EA[4*r+1], a1);
    a2 = fdot2(p2, EA[4*r+2], a2);  a3 = fdot2(p3, EA[4*r+3], a3);
    b0 = fdot2(p0, EB[4*r+0], b0);  b1 = fdot2(p1, EB[4*r+1], b1);
    b2 = fdot2(p2, EB[4*r+2], b2);  b3 = fdot2(p3, EB[4*r+3], b3);
  }
  s0 = (a0 + a1) + (a2 + a3);
  s1 = (b0 + b1) + (b2 + b3);
}

// One block per batch, 128 threads = 2 waves, NO barrier in the main loops.
// Wave 0 (fwd): lane l owns columns 2l,2l+1 of E=exp(lt) as f16 row-pairs.
// Wave 1 (bwd): lane l owns rows    2l,2l+1 of E as f16 col-pairs.
// p-vectors live in LDS as 64 packed h2; exact wave-max normalizer each step.
__global__ __launch_bounds__(128, 1) void crf_fwd_kernel(
    const float* __restrict__ feats,   // [BSZ][T_LEN][N_TAGS]
    const int*   __restrict__ tags,    // [BSZ][T_LEN]
    const int*   __restrict__ mask,    // [BSZ][T_LEN]
    const float* __restrict__ lt,      // [N_TAGS][N_TAGS]
    float*       __restrict__ per_batch)
{
  const int b    = blockIdx.x;
  const int tid  = threadIdx.x;
  const int lane = tid & 63;
  const int wave = tid >> 6;

  __shared__ __align__(16) h2 psF[2][64];
  __shared__ __align__(16) h2 psB[2][64];
  __shared__ float stage[32 * 129];
  __shared__ float bb[N_TAGS];
  __shared__ float sred[2];

  const float* fb = feats + (size_t)b * T_LEN * N_TAGS;
  const int*   tb = tags  + b * T_LEN;

  // ---- sequence length (prefix mask), per-wave independent ----
  int len;
  {
    const i32x4 mv = ((const i32x4*)(mask + b * T_LEN))[lane];
    int v = mv.x + mv.y + mv.z + mv.w;
    #pragma unroll
    for (int d = 1; d < 64; d <<= 1) v += __shfl_xor(v, d);
    len = __builtin_amdgcn_readfirstlane(v);
  }

  // ---- build f16 register-resident E = exp(lt) ----
  // fwd lane l: EA[q]={E[2q][2l],E[2q+1][2l]}, EB same for col 2l+1 (row-pairs).
  // bwd lane l: EA[q]={E[2l][2q],E[2l][2q+1]}, EB same for row 2l+1 (col-pairs).
  h2 EA[64], EB[64];
  #pragma unroll
  for (int c = 0; c < 4; ++c) {
    __syncthreads();
    #pragma unroll
    for (int rr = 0; rr < 32; ++rr)
      stage[rr * 129 + tid] = __expf(lt[(c * 32 + rr) * N_TAGS + tid]);
    __syncthreads();
    if (wave == 0) {
      #pragma unroll
      for (int k = 0; k < 16; ++k) {
        h2 ea, eb;
        ea.x = (_Float16)stage[(2*k)   * 129 + 2*lane];
        ea.y = (_Float16)stage[(2*k+1) * 129 + 2*lane];
        eb.x = (_Float16)stage[(2*k)   * 129 + 2*lane + 1];
        eb.y = (_Float16)stage[(2*k+1) * 129 + 2*lane + 1];
        EA[c*16 + k] = ea;
        EB[c*16 + k] = eb;
      }
    } else if ((lane >> 4) == c) {        // rows 2l,2l+1 live in chunk c
      const int r0 = 2 * lane - 32 * c;
      #pragma unroll
      for (int q = 0; q < 64; ++q) {
        h2 ea, eb;
        ea.x = (_Float16)stage[r0       * 129 + 2*q];
        ea.y = (_Float16)stage[r0       * 129 + 2*q + 1];
        eb.x = (_Float16)stage[(r0 + 1) * 129 + 2*q];
        eb.y = (_Float16)stage[(r0 + 1) * 129 + 2*q + 1];
        EA[q] = ea;
        EB[q] = eb;
      }
    }
  }

  float st0, st1;

  if (wave == 0) {
    // ========== FORWARD: alpha, steps t=1..128 (active iff t<len) ==========
    {
      const float2 f0 = ((const float2*)fb)[lane];
      st0 = lt[ROOT_T * N_TAGS + 2*lane]     + f0.x;
      st1 = lt[ROOT_T * N_TAGS + 2*lane + 1] + f0.y;
    }
    float2 fa = ((const float2*)(fb + 1 * N_TAGS))[lane];
    float2 fc = ((const float2*)(fb + 2 * N_TAGS))[lane];
    float m_cur = wave_max(fmaxf(st0, st1));
    psF[1][lane] = pkrtz(__expf(st0 - m_cur), __expf(st1 - m_cur));

    #pragma unroll 1
    for (int k2 = 0; k2 < 64; ++k2) {
      {                                    // t = 2*k2+1 : read psF[1] -> psF[0]
        const int t = 2 * k2 + 1;
        float s0, s1; dot128(psF[1], EA, EB, s0, s1);
        const float nf0 = m_cur + __logf(s0) + fa.x;
        const float nf1 = m_cur + __logf(s1) + fa.y;
        const bool act = (t < len);
        st0 = act ? nf0 : st0;  st1 = act ? nf1 : st1;
        fa = fc;
        fc = ((const float2*)(fb + (t + 2) * N_TAGS))[lane];
        const float m = wave_max(fmaxf(st0, st1));
        psF[0][lane] = pkrtz(__expf(st0 - m), __expf(st1 - m));
        m_cur = m;
      }
      {                                    // t = 2*k2+2 : read psF[0] -> psF[1]
        const int t = 2 * k2 + 2;
        float s0, s1; dot128(psF[0], EA, EB, s0, s1);
        const float nf0 = m_cur + __logf(s0) + fa.x;
        const float nf1 = m_cur + __logf(s1) + fa.y;
        const bool act = (t < len);
        st0 = act ? nf0 : st0;  st1 = act ? nf1 : st1;
        fa = fc;
        fc = ((const float2*)(fb + (t + 2) * N_TAGS))[lane];
        const float m = wave_max(fmaxf(st0, st1));
        psF[1][lane] = pkrtz(__expf(st0 - m), __expf(st1 - m));
        m_cur = m;
      }
    }
    // st = alpha_128 (frozen at alpha_{len-1} for len<=128)
  } else {
    // ========== BACKWARD: beta, step k applies transition using f[255-k];
    // active iff 256-len <= k <= 126; ends at beta_128. ==========
    st0 = lt[(2*lane)     * N_TAGS + END_T];   // beta_{len-1}
    st1 = lt[(2*lane + 1) * N_TAGS + END_T];
    float2 fw = ((const float2*)(fb + 255 * N_TAGS))[lane];  // f255 (step 0 read)
    float2 fa = ((const float2*)(fb + 254 * N_TAGS))[lane];  // f254 (step 0 write)
    float2 fc = ((const float2*)(fb + 253 * N_TAGS))[lane];
    const float y0i = st0 + fw.x, y1i = st1 + fw.y;
    float m_cur = wave_max(fmaxf(y0i, y1i));
    psB[1][lane] = pkrtz(__expf(y0i - m_cur), __expf(y1i - m_cur));

    const int kmin = 256 - len;              // first active step
    #pragma unroll 1
    for (int k2 = 0; k2 < 64; ++k2) {
      {                                    // k = 2*k2 : read psB[1] -> psB[0]
        const int k = 2 * k2;
        float s0, s1; dot128(psB[1], EA, EB, s0, s1);
        const float nb0 = m_cur + __logf(s0);
        const float nb1 = m_cur + __logf(s1);
        const bool act = (k >= kmin) && (k <= 126);
        st0 = act ? nb0 : st0;  st1 = act ? nb1 : st1;
        const float w0 = fa.x, w1 = fa.y;  // f[254-k]
        fa = fc;
        fc = ((const float2*)(fb + (252 - k) * N_TAGS))[lane];
        const float y0 = st0 + w0, y1 = st1 + w1;
        const float m = wave_max(fmaxf(y0, y1));
        psB[0][lane] = pkrtz(__expf(y0 - m), __expf(y1 - m));
        m_cur = m;
      }
      {                                    // k = 2*k2+1 : read psB[0] -> psB[1]
        const int k = 2 * k2 + 1;
        float s0, s1; dot128(psB[0], EA, EB, s0, s1);
        const float nb0 = m_cur + __logf(s0);
        const float nb1 = m_cur + __logf(s1);
        const bool act = (k >= kmin) && (k <= 126);
        st0 = act ? nb0 : st0;  st1 = act ? nb1 : st1;
        const float w0 = fa.x, w1 = fa.y;
        fa = fc;
        fc = ((const float2*)(fb + (252 - k) * N_TAGS))[lane];
        const float y0 = st0 + w0, y1 = st1 + w1;
        const float m = wave_max(fmaxf(y0, y1));
        psB[1][lane] = pkrtz(__expf(y0 - m), __expf(y1 - m));
        m_cur = m;
      }
    }
    // st = beta_128 (= lt[:,END] when len <= 129)
    bb[2*lane]     = st0;
    bb[2*lane + 1] = st1;
  }
  __syncthreads();

  // ---- gold-path score: 2 timesteps per thread ----
  float c = 0.f;
  #pragma unroll
  for (int q = 0; q < 2; ++q) {
    const int t  = tid + q * N_TAGS;
    const int tg = tb[t];
    if (t == 0)                           c += lt[ROOT_T * N_TAGS + tg];
    if (t >= 1 && t < len)                c += lt[tb[t - 1] * N_TAGS + tg];
    if (t < len && t <= T_LEN - 2)        c += fb[t * N_TAGS + tg];
    if (t == len - 1)                     c += lt[tg * N_TAGS + END_T];
    if (t == T_LEN - 1 && len == T_LEN)   c += fb[t * N_TAGS + tg];
  }
  #pragma unroll
  for (int d = 1; d < 64; d <<= 1) c += __shfl_xor(c, d);
  if (lane == 0) sred[wave] = c;

  // ---- partition: logsumexp(alpha_128 + beta_128), wave 0 ----
  float part = 0.f;
  if (wave == 0) {
    const float x0 = st0 + bb[2*lane];
    const float x1 = st1 + bb[2*lane + 1];
    const float mw = wave_max(fmaxf(x0, x1));
    float e = __expf(x0 - mw) + __expf(x1 - mw);
    #pragma unroll
    for (int d = 1; d < 64; d <<= 1) e += __shfl_xor(e, d);
    part = mw + __logf(e);
  }
  __syncthreads();

  if (tid == 0) per_batch[b] = part - (sred[0] + sred[1]);
}

// Deterministic final reduction: mean over 256 per-batch values.
__global__ __launch_bounds__(256) void crf_reduce_kernel(
    const float* __restrict__ per_batch, float* __restrict__ out)
{
  const int tid = threadIdx.x;
  float v = per_batch[tid] * (1.0f / BSZ);
  #pragma unroll
  for (int d = 1; d < 64; d <<= 1) v += __shfl_xor(v, d);
  __shared__ float r[4];
  if ((tid & 63) == 0) r[tid >> 6] = v;
  __syncthreads();
  if (tid == 0) out[0] = r[0] + r[1] + r[2] + r[3];
}

extern "C" void kernel_launch(void* const* d_in, const int* in_sizes, int n_in,
                              void* d_out, int out_size, void* d_ws, size_t ws_size,
                              hipStream_t stream) {
  (void)in_sizes; (void)n_in; (void)out_size; (void)ws_size;
  const float* feats = (const float*)d_in[0];
  const int*   tags  = (const int*)d_in[1];
  const int*   mask  = (const int*)d_in[2];
  const float* lt    = (const float*)d_in[3];
  float* per_batch = (float*)d_ws;   // 256 floats of scratch

  crf_fwd_kernel<<<BSZ, 128, 0, stream>>>(feats, tags, mask, lt, per_batch);
  crf_reduce_kernel<<<1, 256, 0, stream>>>(per_batch, (float*)d_out);
}

// Round 7
// 74.595 us; speedup vs baseline: 2.6681x; 1.4078x over previous
//
#include <hip/hip_runtime.h>
#include <hip/hip_bf16.h>

#define N_TAGS 128
#define T_LEN  256
#define BSZ    256
#define ROOT_T 126
#define END_T  127

typedef _Float16 h2 __attribute__((ext_vector_type(2)));
typedef _Float16 h8 __attribute__((ext_vector_type(8)));
typedef int   i32x4 __attribute__((ext_vector_type(4)));

static __device__ __forceinline__ h2 pkrtz(float a, float b) {
  return __builtin_bit_cast(h2, __builtin_amdgcn_cvt_pkrtz(a, b));
}

static __device__ __forceinline__ float rfl(float x) {
  return __int_as_float(__builtin_amdgcn_readfirstlane(__float_as_int(x)));
}

static __device__ __forceinline__ float fdot2(h2 a, h2 b, float c) {
#if __has_builtin(__builtin_amdgcn_fdot2)
  return __builtin_amdgcn_fdot2(a, b, c, false);
#else
  float d;
  asm("v_dot2_f32_f16 %0, %1, %2, %3" : "=v"(d) : "v"(a), "v"(b), "v"(c));
  return d;
#endif
}

static __device__ __forceinline__ float wave_max(float x) {
  #pragma unroll
  for (int d = 1; d < 64; d <<= 1) x = fmaxf(x, __shfl_xor(x, d));
  return x;
}

// 128-length dual dot: s0 = sum_k p[k]*EA[k], s1 = sum_k p[k]*EB[k].
// p read from LDS as 16 wave-uniform b128 broadcasts (64 h2), f32 accumulate.
static __device__ __forceinline__ void dot128(const h2* __restrict__ psv,
                                              const h2 (&EA)[64], const h2 (&EB)[64],
                                              float& s0, float& s1) {
  const h8* pv = (const h8*)psv;
  float a0=0.f,a1=0.f,a2=0.f,a3=0.f, b0=0.f,b1=0.f,b2=0.f,b3=0.f;
  #pragma unroll
  for (int r = 0; r < 16; ++r) {
    const h8 v = pv[r];
    const h2 p0 = __builtin_shufflevector(v, v, 0, 1);
    const h2 p1 = __builtin_shufflevector(v, v, 2, 3);
    const h2 p2 = __builtin_shufflevector(v, v, 4, 5);
    const h2 p3 = __builtin_shufflevector(v, v, 6, 7);
    a0 = fdot2(p0, EA[4*r+0], a0);  a1 = fdot2(p1, EA[4*r+1], a1);
    a2 = fdot2(p2, EA[4*r+2], a2);  a3 = fdot2(p3, EA[4*r+3], a3);
    b0 = fdot2(p0, EB[4*r+0], b0);  b1 = fdot2(p1, EB[4*r+1], b1);
    b2 = fdot2(p2, EB[4*r+2], b2);  b3 = fdot2(p3, EB[4*r+3], b3);
  }
  s0 = (a0 + a1) + (a2 + a3);
  s1 = (b0 + b1) + (b2 + b3);
}

// One block per batch, 128 threads = 2 waves, NO barrier in the main loops.
// Wave 0 (fwd): lane l owns columns 2l,2l+1 of E=exp(lt) as f16 row-pairs.
// Wave 1 (bwd): lane l owns rows    2l,2l+1 of E as f16 col-pairs.
// p-vectors live in LDS as 64 packed h2.
// Normalizer: readfirstlane of lane0's state (+2 headroom) -- no shuffle chain.
// waves_per_eu(1,1) forces the full arch-VGPR budget so EA/EB stay in VGPRs
// (round 6: VGPR_Count=88 -> arrays in AGPRs -> v_accvgpr_read per fdot2).
__global__ void
__attribute__((amdgpu_flat_work_group_size(128, 128), amdgpu_waves_per_eu(1, 1)))
crf_fwd_kernel(
    const float* __restrict__ feats,   // [BSZ][T_LEN][N_TAGS]
    const int*   __restrict__ tags,    // [BSZ][T_LEN]
    const int*   __restrict__ mask,    // [BSZ][T_LEN]
    const float* __restrict__ lt,      // [N_TAGS][N_TAGS]
    float*       __restrict__ per_batch)
{
  const int b    = blockIdx.x;
  const int tid  = threadIdx.x;
  const int lane = tid & 63;
  const int wave = tid >> 6;

  __shared__ __align__(16) h2 psF[2][64];
  __shared__ __align__(16) h2 psB[2][64];
  __shared__ float stage[32 * 129];
  __shared__ float bb[N_TAGS];
  __shared__ float sred[2];

  const float* fb = feats + (size_t)b * T_LEN * N_TAGS;
  const int*   tb = tags  + b * T_LEN;

  // ---- sequence length (prefix mask), per-wave independent ----
  int len;
  {
    const i32x4 mv = ((const i32x4*)(mask + b * T_LEN))[lane];
    int v = mv.x + mv.y + mv.z + mv.w;
    #pragma unroll
    for (int d = 1; d < 64; d <<= 1) v += __shfl_xor(v, d);
    len = __builtin_amdgcn_readfirstlane(v);
  }

  // ---- build f16 register-resident E = exp(lt) ----
  // fwd lane l: EA[q]={E[2q][2l],E[2q+1][2l]}, EB same for col 2l+1 (row-pairs).
  // bwd lane l: EA[q]={E[2l][2q],E[2l][2q+1]}, EB same for row 2l+1 (col-pairs).
  h2 EA[64], EB[64];
  #pragma unroll
  for (int c = 0; c < 4; ++c) {
    __syncthreads();
    #pragma unroll
    for (int rr = 0; rr < 32; ++rr)
      stage[rr * 129 + tid] = __expf(lt[(c * 32 + rr) * N_TAGS + tid]);
    __syncthreads();
    if (wave == 0) {
      #pragma unroll
      for (int k = 0; k < 16; ++k) {
        h2 ea, eb;
        ea.x = (_Float16)stage[(2*k)   * 129 + 2*lane];
        ea.y = (_Float16)stage[(2*k+1) * 129 + 2*lane];
        eb.x = (_Float16)stage[(2*k)   * 129 + 2*lane + 1];
        eb.y = (_Float16)stage[(2*k+1) * 129 + 2*lane + 1];
        EA[c*16 + k] = ea;
        EB[c*16 + k] = eb;
      }
    } else if ((lane >> 4) == c) {        // rows 2l,2l+1 live in chunk c
      const int r0 = 2 * lane - 32 * c;
      #pragma unroll
      for (int q = 0; q < 64; ++q) {
        h2 ea, eb;
        ea.x = (_Float16)stage[r0       * 129 + 2*q];
        ea.y = (_Float16)stage[r0       * 129 + 2*q + 1];
        eb.x = (_Float16)stage[(r0 + 1) * 129 + 2*q];
        eb.y = (_Float16)stage[(r0 + 1) * 129 + 2*q + 1];
        EA[q] = ea;
        EB[q] = eb;
      }
    }
  }

  float st0, st1;

  if (wave == 0) {
    // ========== FORWARD: alpha, steps t=1..128 (active iff t<len) ==========
    {
      const float2 f0 = ((const float2*)fb)[lane];
      st0 = lt[ROOT_T * N_TAGS + 2*lane]     + f0.x;
      st1 = lt[ROOT_T * N_TAGS + 2*lane + 1] + f0.y;
    }
    float2 fa = ((const float2*)(fb + 1 * N_TAGS))[lane];
    float2 fc = ((const float2*)(fb + 2 * N_TAGS))[lane];
    float m_cur = rfl(st0) + 2.0f;
    psF[1][lane] = pkrtz(__expf(st0 - m_cur), __expf(st1 - m_cur));

    #pragma unroll 1
    for (int k2 = 0; k2 < 64; ++k2) {
      {                                    // t = 2*k2+1 : read psF[1] -> psF[0]
        const int t = 2 * k2 + 1;
        float s0, s1; dot128(psF[1], EA, EB, s0, s1);
        const float nf0 = m_cur + __logf(s0) + fa.x;
        const float nf1 = m_cur + __logf(s1) + fa.y;
        const bool act = (t < len);
        st0 = act ? nf0 : st0;  st1 = act ? nf1 : st1;
        fa = fc;
        fc = ((const float2*)(fb + (t + 2) * N_TAGS))[lane];
        const float m = rfl(st0) + 2.0f;
        psF[0][lane] = pkrtz(__expf(st0 - m), __expf(st1 - m));
        m_cur = m;
      }
      {                                    // t = 2*k2+2 : read psF[0] -> psF[1]
        const int t = 2 * k2 + 2;
        float s0, s1; dot128(psF[0], EA, EB, s0, s1);
        const float nf0 = m_cur + __logf(s0) + fa.x;
        const float nf1 = m_cur + __logf(s1) + fa.y;
        const bool act = (t < len);
        st0 = act ? nf0 : st0;  st1 = act ? nf1 : st1;
        fa = fc;
        fc = ((const float2*)(fb + (t + 2) * N_TAGS))[lane];
        const float m = rfl(st0) + 2.0f;
        psF[1][lane] = pkrtz(__expf(st0 - m), __expf(st1 - m));
        m_cur = m;
      }
    }
    // st = alpha_128 (frozen at alpha_{len-1} for len<=128)
  } else {
    // ========== BACKWARD: beta, step k applies transition using f[255-k];
    // active iff 256-len <= k <= 126; ends at beta_128. ==========
    st0 = lt[(2*lane)     * N_TAGS + END_T];   // beta_{len-1}
    st1 = lt[(2*lane + 1) * N_TAGS + END_T];
    float2 fw = ((const float2*)(fb + 255 * N_TAGS))[lane];  // f255 (step 0 read)
    float2 fa = ((const float2*)(fb + 254 * N_TAGS))[lane];  // f254 (step 0 write)
    float2 fc = ((const float2*)(fb + 253 * N_TAGS))[lane];
    const float y0i = st0 + fw.x, y1i = st1 + fw.y;
    float m_cur = rfl(y0i) + 2.0f;
    psB[1][lane] = pkrtz(__expf(y0i - m_cur), __expf(y1i - m_cur));

    const int kmin = 256 - len;              // first active step
    #pragma unroll 1
    for (int k2 = 0; k2 < 64; ++k2) {
      {                                    // k = 2*k2 : read psB[1] -> psB[0]
        const int k = 2 * k2;
        float s0, s1; dot128(psB[1], EA, EB, s0, s1);
        const float nb0 = m_cur + __logf(s0);
        const float nb1 = m_cur + __logf(s1);
        const bool act = (k >= kmin) && (k <= 126);
        st0 = act ? nb0 : st0;  st1 = act ? nb1 : st1;
        const float w0 = fa.x, w1 = fa.y;  // f[254-k]
        fa = fc;
        fc = ((const float2*)(fb + (252 - k) * N_TAGS))[lane];
        const float y0 = st0 + w0, y1 = st1 + w1;
        const float m = rfl(y0) + 2.0f;
        psB[0][lane] = pkrtz(__expf(y0 - m), __expf(y1 - m));
        m_cur = m;
      }
      {                                    // k = 2*k2+1 : read psB[0] -> psB[1]
        const int k = 2 * k2 + 1;
        float s0, s1; dot128(psB[0], EA, EB, s0, s1);
        const float nb0 = m_cur + __logf(s0);
        const float nb1 = m_cur + __logf(s1);
        const bool act = (k >= kmin) && (k <= 126);
        st0 = act ? nb0 : st0;  st1 = act ? nb1 : st1;
        const float w0 = fa.x, w1 = fa.y;
        fa = fc;
        fc = ((const float2*)(fb + (252 - k) * N_TAGS))[lane];
        const float y0 = st0 + w0, y1 = st1 + w1;
        const float m = rfl(y0) + 2.0f;
        psB[1][lane] = pkrtz(__expf(y0 - m), __expf(y1 - m));
        m_cur = m;
      }
    }
    // st = beta_128 (= lt[:,END] when len <= 129)
    bb[2*lane]     = st0;
    bb[2*lane + 1] = st1;
  }
  __syncthreads();

  // ---- gold-path score: 2 timesteps per thread ----
  float c = 0.f;
  #pragma unroll
  for (int q = 0; q < 2; ++q) {
    const int t  = tid + q * N_TAGS;
    const int tg = tb[t];
    if (t == 0)                           c += lt[ROOT_T * N_TAGS + tg];
    if (t >= 1 && t < len)                c += lt[tb[t - 1] * N_TAGS + tg];
    if (t < len && t <= T_LEN - 2)        c += fb[t * N_TAGS + tg];
    if (t == len - 1)                     c += lt[tg * N_TAGS + END_T];
    if (t == T_LEN - 1 && len == T_LEN)   c += fb[t * N_TAGS + tg];
  }
  #pragma unroll
  for (int d = 1; d < 64; d <<= 1) c += __shfl_xor(c, d);
  if (lane == 0) sred[wave] = c;

  // ---- partition: logsumexp(alpha_128 + beta_128), wave 0 ----
  float part = 0.f;
  if (wave == 0) {
    const float x0 = st0 + bb[2*lane];
    const float x1 = st1 + bb[2*lane + 1];
    const float mw = wave_max(fmaxf(x0, x1));
    float e = __expf(x0 - mw) + __expf(x1 - mw);
    #pragma unroll
    for (int d = 1; d < 64; d <<= 1) e += __shfl_xor(e, d);
    part = mw + __logf(e);
  }
  __syncthreads();

  if (tid == 0) per_batch[b] = part - (sred[0] + sred[1]);
}

// Deterministic final reduction: mean over 256 per-batch values.
__global__ __launch_bounds__(256) void crf_reduce_kernel(
    const float* __restrict__ per_batch, float* __restrict__ out)
{
  const int tid = threadIdx.x;
  float v = per_batch[tid] * (1.0f / BSZ);
  #pragma unroll
  for (int d = 1; d < 64; d <<= 1) v += __shfl_xor(v, d);
  __shared__ float r[4];
  if ((tid & 63) == 0) r[tid >> 6] = v;
  __syncthreads();
  if (tid == 0) out[0] = r[0] + r[1] + r[2] + r[3];
}

extern "C" void kernel_launch(void* const* d_in, const int* in_sizes, int n_in,
                              void* d_out, int out_size, void* d_ws, size_t ws_size,
                              hipStream_t stream) {
  (void)in_sizes; (void)n_in; (void)out_size; (void)ws_size;
  const float* feats = (const float*)d_in[0];
  const int*   tags  = (const int*)d_in[1];
  const int*   mask  = (const int*)d_in[2];
  const float* lt    = (const float*)d_in[3];
  float* per_batch = (float*)d_ws;   // 256 floats of scratch

  crf_fwd_kernel<<<BSZ, 128, 0, stream>>>(feats, tags, mask, lt, per_batch);
  crf_reduce_kernel<<<1, 256, 0, stream>>>(per_batch, (float*)d_out);
}